// Round 6
// baseline (1797.177 us; speedup 1.0000x reference)
//
#include <hip/hip_runtime.h>
#include <hip/hip_bf16.h>
#include <stdint.h>

typedef unsigned int uint32;
typedef unsigned long long uint64;
typedef __attribute__((ext_vector_type(8))) short short8;
typedef __attribute__((ext_vector_type(4))) float f32x4;

#define NB 128
#define NT 256
#define NH 512
#define NE 80
#define NCH 128
#define NL 784
#define NV 500
#define NG4 2048

__device__ __forceinline__ unsigned short f2bf(float f){
  union { float f; unsigned int i; } v; v.f = f;
  unsigned int r = v.i + 0x7FFFu + ((v.i >> 16) & 1u);
  return (unsigned short)(r >> 16);
}
__device__ __forceinline__ float sigf(float x){ return 1.0f/(1.0f + __expf(-x)); }
__device__ __forceinline__ float tanhfast(float x){ return 1.0f - 2.0f/(__expf(2.0f*x)+1.0f); }

// ---------------- K1: mean over L (f32 inputs) ----------------
__global__ void k_mean(const float* __restrict__ lat, float* __restrict__ meanv){
  int b = blockIdx.x;
  int tid = threadIdx.x;          // 256
  int c4 = tid & 31;
  int part = tid >> 5;
  const float4* row = (const float4*)(lat + (size_t)b*NL*NCH);
  float sx=0.f, sy=0.f, sz=0.f, sw=0.f;
  for (int l=part; l<NL; l+=8){
    float4 v = row[l*32 + c4];
    sx+=v.x; sy+=v.y; sz+=v.z; sw+=v.w;
  }
  __shared__ float red[8][32][4];
  red[part][c4][0]=sx; red[part][c4][1]=sy; red[part][c4][2]=sz; red[part][c4][3]=sw;
  __syncthreads();
  if (part==0){
    float a0=0,a1=0,a2=0,a3=0;
    #pragma unroll
    for (int p=0;p<8;p++){ a0+=red[p][c4][0]; a1+=red[p][c4][1]; a2+=red[p][c4][2]; a3+=red[p][c4][3]; }
    float4 o; o.x=a0*(1.0f/NL); o.y=a1*(1.0f/NL); o.z=a2*(1.0f/NL); o.w=a3*(1.0f/NL);
    ((float4*)meanv)[b*32 + c4] = o;
  }
}

// ---------------- K2: h0/c0/o0 + initial tagged h buffer (tag 0) ----------------
__global__ void k_init(const float* __restrict__ meanv,
    const float* __restrict__ Wh, const float* __restrict__ bh,
    const float* __restrict__ Wc, const float* __restrict__ bc,
    const float* __restrict__ Wo, const float* __restrict__ bo,
    float* __restrict__ c0, float* __restrict__ o0, uint32* __restrict__ hbuf){
  int b = blockIdx.x; int j = threadIdx.x;  // 512 threads
  const float* m = meanv + b*NCH;
  const float4* wh = (const float4*)(Wh + (size_t)j*NCH);
  const float4* wc = (const float4*)(Wc + (size_t)j*NCH);
  const float4* wo = (const float4*)(Wo + (size_t)j*NCH);
  float sh=0.f, sc=0.f, so=0.f;
  for (int c=0; c<NCH/4; c++){
    float4 vh = wh[c], vc = wc[c], vo = wo[c];
    float m0=m[c*4], m1=m[c*4+1], m2=m[c*4+2], m3=m[c*4+3];
    sh += m0*vh.x + m1*vh.y + m2*vh.z + m3*vh.w;
    sc += m0*vc.x + m1*vc.y + m2*vc.z + m3*vc.w;
    so += m0*vo.x + m1*vo.y + m2*vo.z + m3*vo.w;
  }
  float h0 = tanhf(sh + bh[j]);
  c0[b*NH+j] = tanhf(sc + bc[j]);
  o0[b*NH+j] = tanhf(so + bo[j]);
  hbuf[(size_t)b*NH + j] = (uint32)f2bf(h0);   // tag (hi 16) = 0
}

// ---------------- K3: per-token gate table = emb @ W_ih[:,512:].T ----------------
__global__ void k_table(const float* __restrict__ emb,
                        const float* __restrict__ Wih,
                        float* __restrict__ table){
  int v = blockIdx.x;
  int n = blockIdx.y*256 + threadIdx.x;
  const float4* wr = (const float4*)(Wih + (size_t)n*(NH+NE) + NH);
  const float4* er = (const float4*)(emb + v*NE);
  float s = 0.f;
  for (int e4=0; e4<NE/4; e4++){
    float4 w = wr[e4], e = er[e4];
    s += w.x*e.x + w.y*e.y + w.z*e.z + w.w*e.w;
  }
  table[(size_t)v*NG4 + n] = s;
}

// ---------------- K4: base = o0 @ W_ih[:,:512].T + b_ih + b_hh ----------------
__global__ void k_base(const float* __restrict__ o0,
                       const float* __restrict__ Wih,
                       const float* __restrict__ bih,
                       const float* __restrict__ bhh,
                       float* __restrict__ base){
  int b = blockIdx.x;
  int n = blockIdx.y*256 + threadIdx.x;
  const float4* o = (const float4*)(o0 + b*NH);
  const float4* wr = (const float4*)(Wih + (size_t)n*(NH+NE));
  float s = bih[n] + bhh[n];
  for (int k4=0;k4<NH/4;k4++){
    float4 w = wr[k4], v = o[k4];
    s += w.x*v.x + w.y*v.y + w.z*v.z + w.w*v.w;
  }
  base[(size_t)b*NG4 + n] = s;
}

// ---------------- K5: sequential LSTM, no-sync per-chunk dataflow ----------------
// 128 blocks = 8 groups (16 rows) x 16 slices (32 units). 2 waves/block.
// Wave w owns units u0 + w*16 + (lane&15): all 4 gates in-register (tiles
// {gate, uhalf=w}) -> in-register epilogue, no LDS, no __syncthreads.
// h: tagged uint32 (step<<16 | bf16) per unit; 8B pair-stores; consumers
// load A-fragments straight from hbuf, per-K-chunk spin, depth-8 pipeline.
__global__ __launch_bounds__(128, 1) void k_lstm(
    const float* __restrict__ Whh,
    const int* __restrict__ formulas,
    const float* __restrict__ table,
    const float* __restrict__ base,
    const float* __restrict__ c0,
    uint32* hbuf,
    float* __restrict__ out)
{
  int bid = blockIdx.x;
  int g = bid & 7, s = bid >> 3;
  int tid = threadIdx.x;
  int lane = tid & 63, w = tid >> 6;        // 2 waves
  int b0 = g*16, u0 = s*32;
  int col = lane & 15;                      // A-row / C-col / unit-in-half
  int hi  = lane >> 4;                      // 0..3
  int myunit = u0 + w*16 + col;             // global hidden unit (this lane)
  int r0 = hi*4;                            // epilogue row base (C rows hi*4+r)

  // ---- B fragments: bwf[gt][j] for K-chunk ksd=(j+s)&15 (rotation baked in)
  short8 bwf0[16], bwf1[16], bwf2[16], bwf3[16];
  {
    #pragma unroll
    for (int j=0;j<16;j++){
      int ksd = (j + s) & 15;
      int kof = ksd*32 + hi*8;
      #pragma unroll
      for (int gt=0; gt<4; gt++){
        const float4* p4 = (const float4*)(Whh + (size_t)(gt*NH + myunit)*NH + kof);
        float4 lo = p4[0], hp = p4[1];
        short8 tv;
        tv[0]=(short)f2bf(lo.x); tv[1]=(short)f2bf(lo.y); tv[2]=(short)f2bf(lo.z); tv[3]=(short)f2bf(lo.w);
        tv[4]=(short)f2bf(hp.x); tv[5]=(short)f2bf(hp.y); tv[6]=(short)f2bf(hp.z); tv[7]=(short)f2bf(hp.w);
        if (gt==0) bwf0[j]=tv; else if (gt==1) bwf1[j]=tv; else if (gt==2) bwf2[j]=tv; else bwf3[j]=tv;
      }
    }
  }

  // ---- per-lane state: c for 4 rows of my unit; base/table biases [row][gate]
  float cst[4];
  float bs[4][4], tb[4][4];
  #pragma unroll
  for (int r=0;r<4;r++){
    int be = b0 + r0 + r;
    cst[r] = c0[be*NH + myunit];
    #pragma unroll
    for (int gt=0; gt<4; gt++)
      bs[r][gt] = base[(size_t)be*NG4 + gt*NH + myunit];
    int tok0 = formulas[be*NT + 0];
    #pragma unroll
    for (int gt=0; gt<4; gt++)
      tb[r][gt] = table[(size_t)tok0*NG4 + gt*NH + myunit];
  }

  // A-load base (uint64 index within an h buffer): row=col, k-offset hi*8
  int abase = (b0 + col)*(NH/2) + hi*4;

  for (int t=0; t<NT; t++){
    const uint64* hrd64 = (const uint64*)(hbuf + (size_t)(t & 1)*NB*NH);
    uint64*       hwr64 = (uint64*)      (hbuf + (size_t)((t+1) & 1)*NB*NH);
    const uint32 etag = (uint32)t;

    uint64 vv[16][4];
    #define LOADC(j_) { int ksd = ((j_) + s) & 15;                                   \
      const uint64* p_ = hrd64 + abase + ksd*16;                                     \
      vv[j_][0] = __hip_atomic_load(p_+0, __ATOMIC_RELAXED, __HIP_MEMORY_SCOPE_AGENT); \
      vv[j_][1] = __hip_atomic_load(p_+1, __ATOMIC_RELAXED, __HIP_MEMORY_SCOPE_AGENT); \
      vv[j_][2] = __hip_atomic_load(p_+2, __ATOMIC_RELAXED, __HIP_MEMORY_SCOPE_AGENT); \
      vv[j_][3] = __hip_atomic_load(p_+3, __ATOMIC_RELAXED, __HIP_MEMORY_SCOPE_AGENT); }
    #define TAGDIFF(j_) (((((uint32)(vv[j_][0] >> 16)) ^ etag) & 0xFFFFu) |          \
                         ((((uint32)(vv[j_][1] >> 16)) ^ etag) & 0xFFFFu) |          \
                         ((((uint32)(vv[j_][2] >> 16)) ^ etag) & 0xFFFFu) |          \
                         ((((uint32)(vv[j_][3] >> 16)) ^ etag) & 0xFFFFu))

    // prologue: 8 chunks in flight
    #pragma unroll
    for (int j=0;j<8;j++) LOADC(j);

    f32x4 acc0 = {0.f,0.f,0.f,0.f}, acc1 = {0.f,0.f,0.f,0.f};
    f32x4 acc2 = {0.f,0.f,0.f,0.f}, acc3 = {0.f,0.f,0.f,0.f};

    #pragma unroll
    for (int j=0;j<16;j++){
      // spin until this chunk's 4 tagged pairs are step-t (wave-coherent)
      uint32 d = TAGDIFF(j);
      int guard = 0;
      while (!__all(d == 0)){
        LOADC(j);
        d = TAGDIFF(j);
        if (++guard > (1<<14)) break;
      }
      if (j < 8) LOADC(j+8);
      // pack A-fragment: low16 of 8 tagged dwords -> short8
      uint32 a0 = __builtin_amdgcn_perm((uint32)(vv[j][0] >> 32), (uint32)vv[j][0], 0x05040100u);
      uint32 a1 = __builtin_amdgcn_perm((uint32)(vv[j][1] >> 32), (uint32)vv[j][1], 0x05040100u);
      uint32 a2 = __builtin_amdgcn_perm((uint32)(vv[j][2] >> 32), (uint32)vv[j][2], 0x05040100u);
      uint32 a3 = __builtin_amdgcn_perm((uint32)(vv[j][3] >> 32), (uint32)vv[j][3], 0x05040100u);
      union { uint32 u[4]; short8 s8; } af;
      af.u[0]=a0; af.u[1]=a1; af.u[2]=a2; af.u[3]=a3;
      acc0 = __builtin_amdgcn_mfma_f32_16x16x32_bf16(af.s8, bwf0[j], acc0, 0, 0, 0);
      acc1 = __builtin_amdgcn_mfma_f32_16x16x32_bf16(af.s8, bwf1[j], acc1, 0, 0, 0);
      acc2 = __builtin_amdgcn_mfma_f32_16x16x32_bf16(af.s8, bwf2[j], acc2, 0, 0, 0);
      acc3 = __builtin_amdgcn_mfma_f32_16x16x32_bf16(af.s8, bwf3[j], acc3, 0, 0, 0);
    }
    #undef LOADC
    #undef TAGDIFF

    // ---- in-register epilogue: 4 rows x 1 unit per lane
    #pragma unroll
    for (int r=0;r<4;r++){
      int be = b0 + r0 + r;
      float gi = acc0[r] + tb[r][0] + bs[r][0];
      float gf = acc1[r] + tb[r][1] + bs[r][1];
      float gg = acc2[r] + tb[r][2] + bs[r][2];
      float go = acc3[r] + tb[r][3] + bs[r][3];
      float cn = sigf(gf)*cst[r] + sigf(gi)*tanhfast(gg);
      cst[r] = cn;
      float hn = sigf(go)*tanhfast(cn);

      // publish tagged pair (even lane stores 8B for units {u, u+1})
      if (t < NT-1){
        uint32 tagged = ((uint32)(t+1) << 16) | (uint32)f2bf(hn);
        uint32 ptag = (uint32)__shfl_xor((int)tagged, 1);
        if ((lane & 1) == 0){
          uint64 pv = (uint64)tagged | ((uint64)ptag << 32);
          __hip_atomic_store(hwr64 + (((size_t)be*NH + myunit) >> 1), pv,
                             __ATOMIC_RELAXED, __HIP_MEMORY_SCOPE_AGENT);
        }
      }
      // output store (pair-packed f32x2 from even lanes)
      float ph = __shfl_xor(hn, 1);
      if ((lane & 1) == 0){
        float2 ov; ov.x = hn; ov.y = ph;
        *(float2*)(out + ((size_t)be*NT + t)*NH + myunit) = ov;
      }
    }

    // ---- next-token table prefetch (off critical path)
    if (t < NT-1){
      #pragma unroll
      for (int r=0;r<4;r++){
        int be = b0 + r0 + r;
        int tokn = formulas[be*NT + t + 1];
        #pragma unroll
        for (int gt=0; gt<4; gt++)
          tb[r][gt] = table[(size_t)tokn*NG4 + gt*NH + myunit];
      }
    }
  }
}

extern "C" void kernel_launch(void* const* d_in, const int* in_sizes, int n_in,
                              void* d_out, int out_size, void* d_ws, size_t ws_size,
                              hipStream_t stream) {
  const float* lat      = (const float*)d_in[0];
  const int*   formulas = (const int*)d_in[1];
  const float* emb      = (const float*)d_in[2];
  const float* Wih      = (const float*)d_in[3];
  const float* bih      = (const float*)d_in[4];
  const float* Whh      = (const float*)d_in[5];
  const float* bhh      = (const float*)d_in[6];
  const float* Wh       = (const float*)d_in[7];
  const float* bh       = (const float*)d_in[8];
  const float* Wc       = (const float*)d_in[9];
  const float* bc       = (const float*)d_in[10];
  const float* Wo       = (const float*)d_in[11];
  const float* bo       = (const float*)d_in[12];
  float* out = (float*)d_out;

  char* ws = (char*)d_ws;
  float* meanv = (float*)ws;  ws += (size_t)NB*NCH*4;        // 64 KB
  float* c0    = (float*)ws;  ws += (size_t)NB*NH*4;         // 256 KB
  float* o0    = (float*)ws;  ws += (size_t)NB*NH*4;         // 256 KB
  float* table = (float*)ws;  ws += (size_t)NV*NG4*4;        // 4 MB
  float* base  = (float*)ws;  ws += (size_t)NB*NG4*4;        // 1 MB
  uint32* hbuf = (uint32*)ws; ws += (size_t)2*NB*NH*4;       // 512 KB (tagged, dbuf)

  // clear tags each launch — REQUIRED (tag collision with prior replay at t>=254)
  hipMemsetAsync(hbuf, 0, (size_t)2*NB*NH*4, stream);
  k_mean <<<NB, 256, 0, stream>>>(lat, meanv);
  k_init <<<NB, NH, 0, stream>>>(meanv, Wh, bh, Wc, bc, Wo, bo, c0, o0, hbuf);
  k_table<<<dim3(NV, 8), 256, 0, stream>>>(emb, Wih, table);
  k_base <<<dim3(NB, 8), 256, 0, stream>>>(o0, Wih, bih, bhh, base);
  k_lstm <<<NB, 128, 0, stream>>>(Whh, formulas, table, base, c0, hbuf, out);
}

// Round 7
// 1225.224 us; speedup vs baseline: 1.4668x; 1.4668x over previous
//
#include <hip/hip_runtime.h>
#include <hip/hip_bf16.h>
#include <stdint.h>

typedef unsigned int uint32;
typedef unsigned long long uint64;
typedef __attribute__((ext_vector_type(8))) short short8;
typedef __attribute__((ext_vector_type(4))) float f32x4;

#define NB 128
#define NT 256
#define NH 512
#define NE 80
#define NCH 128
#define NL 784
#define NV 500
#define NG4 2048

// tagged h exchange: [buf][group g][chunk ks][row r][unit-pair p] as uint64
// (two tagged uint32 words: (step<<16)|bf16), 256 uint64 per chunk.
#define HB64 (8*16*256)   // uint64 per buffer (32768)

__device__ __forceinline__ unsigned short f2bf(float f){
  union { float f; unsigned int i; } v; v.f = f;
  unsigned int r = v.i + 0x7FFFu + ((v.i >> 16) & 1u);
  return (unsigned short)(r >> 16);
}
__device__ __forceinline__ float sigf(float x){ return 1.0f/(1.0f + __expf(-x)); }
__device__ __forceinline__ float tanhfast(float x){ return 1.0f - 2.0f/(__expf(2.0f*x)+1.0f); }

// ---------------- K1: mean over L (f32 inputs) ----------------
__global__ void k_mean(const float* __restrict__ lat, float* __restrict__ meanv){
  int b = blockIdx.x;
  int tid = threadIdx.x;          // 256
  int c4 = tid & 31;
  int part = tid >> 5;
  const float4* row = (const float4*)(lat + (size_t)b*NL*NCH);
  float sx=0.f, sy=0.f, sz=0.f, sw=0.f;
  for (int l=part; l<NL; l+=8){
    float4 v = row[l*32 + c4];
    sx+=v.x; sy+=v.y; sz+=v.z; sw+=v.w;
  }
  __shared__ float red[8][32][4];
  red[part][c4][0]=sx; red[part][c4][1]=sy; red[part][c4][2]=sz; red[part][c4][3]=sw;
  __syncthreads();
  if (part==0){
    float a0=0,a1=0,a2=0,a3=0;
    #pragma unroll
    for (int p=0;p<8;p++){ a0+=red[p][c4][0]; a1+=red[p][c4][1]; a2+=red[p][c4][2]; a3+=red[p][c4][3]; }
    float4 o; o.x=a0*(1.0f/NL); o.y=a1*(1.0f/NL); o.z=a2*(1.0f/NL); o.w=a3*(1.0f/NL);
    ((float4*)meanv)[b*32 + c4] = o;
  }
}

// ---------------- K2: h0/c0/o0 + initial tagged h buffer (tag 0, chunked layout) ----------------
__global__ void k_init(const float* __restrict__ meanv,
    const float* __restrict__ Wh, const float* __restrict__ bh,
    const float* __restrict__ Wc, const float* __restrict__ bc,
    const float* __restrict__ Wo, const float* __restrict__ bo,
    float* __restrict__ c0, float* __restrict__ o0, uint64* __restrict__ hbuf){
  int b = blockIdx.x; int j = threadIdx.x;  // 512 threads; b = batch row
  __shared__ unsigned short hsh[NH];
  const float* m = meanv + b*NCH;
  const float4* wh = (const float4*)(Wh + (size_t)j*NCH);
  const float4* wc = (const float4*)(Wc + (size_t)j*NCH);
  const float4* wo = (const float4*)(Wo + (size_t)j*NCH);
  float sh=0.f, sc=0.f, so=0.f;
  for (int c=0; c<NCH/4; c++){
    float4 vh = wh[c], vc = wc[c], vo = wo[c];
    float m0=m[c*4], m1=m[c*4+1], m2=m[c*4+2], m3=m[c*4+3];
    sh += m0*vh.x + m1*vh.y + m2*vh.z + m3*vh.w;
    sc += m0*vc.x + m1*vc.y + m2*vc.z + m3*vc.w;
    so += m0*vo.x + m1*vo.y + m2*vo.z + m3*vo.w;
  }
  float h0 = tanhf(sh + bh[j]);
  c0[b*NH+j] = tanhf(sc + bc[j]);
  o0[b*NH+j] = tanhf(so + bo[j]);
  hsh[j] = f2bf(h0);
  __syncthreads();
  if (j < NH/2){
    // pair p=j: units 2j,2j+1; chunk cs=j>>4; pair-in-chunk j&15
    int g = b >> 4, r = b & 15, cs = j >> 4;
    uint64 pv = (uint64)(uint32)hsh[2*j] | ((uint64)(uint32)hsh[2*j+1] << 32); // tags=0
    hbuf[(size_t)(g*16 + cs)*256 + r*16 + (j & 15)] = pv;
  }
}

// ---------------- K3: per-token gate table = emb @ W_ih[:,512:].T ----------------
__global__ void k_table(const float* __restrict__ emb,
                        const float* __restrict__ Wih,
                        float* __restrict__ table){
  int v = blockIdx.x;
  int n = blockIdx.y*256 + threadIdx.x;
  const float4* wr = (const float4*)(Wih + (size_t)n*(NH+NE) + NH);
  const float4* er = (const float4*)(emb + v*NE);
  float s = 0.f;
  for (int e4=0; e4<NE/4; e4++){
    float4 w = wr[e4], e = er[e4];
    s += w.x*e.x + w.y*e.y + w.z*e.z + w.w*e.w;
  }
  table[(size_t)v*NG4 + n] = s;
}

// ---------------- K4: base = o0 @ W_ih[:,:512].T + b_ih + b_hh ----------------
__global__ void k_base(const float* __restrict__ o0,
                       const float* __restrict__ Wih,
                       const float* __restrict__ bih,
                       const float* __restrict__ bhh,
                       float* __restrict__ base){
  int b = blockIdx.x;
  int n = blockIdx.y*256 + threadIdx.x;
  const float4* o = (const float4*)(o0 + b*NH);
  const float4* wr = (const float4*)(Wih + (size_t)n*(NH+NE));
  float s = bih[n] + bhh[n];
  for (int k4=0;k4<NH/4;k4++){
    float4 w = wr[k4], v = o[k4];
    s += w.x*v.x + w.y*v.y + w.z*v.z + w.w*v.w;
  }
  base[(size_t)b*NG4 + n] = s;
}

// ---------------- K5: sequential LSTM, per-chunk streaming ----------------
// 128 blocks = 8 groups (16 rows) x 16 slices (32 units). 256 thr / 4 waves.
// Wave w OWNS chunks {w, w+4, w+8, w+12}: polls them from global (tagged),
// packs, stages to LDS, release-stores ready[ks]=t. MFMA loop consumes own
// chunks from registers, others from LDS after a cheap LDS-flag spin.
// One __syncthreads per step (G double-buffered by parity).
__global__ __launch_bounds__(256, 1) void k_lstm(
    const float* __restrict__ Whh,
    const int* __restrict__ formulas,
    const float* __restrict__ table,
    const float* __restrict__ base,
    const float* __restrict__ c0,
    uint64* hbuf,
    float* __restrict__ out)
{
  int bid = blockIdx.x;
  int g = bid & 7, s = bid >> 3;
  int tid = threadIdx.x;
  int lane = tid & 63, w = tid >> 6;
  int b0 = g*16, u0 = s*32;
  int row = lane & 15, hi = lane >> 4;
  int slot = hi ^ (row & 3);                 // LDS bank spread

  __shared__ __align__(16) char h_lds[16*1024];   // [chunk][row][32 units] bf16, slot-swizzled
  __shared__ float G[2][16*132 + 4];              // gate exchange, parity-buffered
  __shared__ int ready[16];

  if (tid < 16) ready[tid] = -1;

  // ---- B fragments in EXECUTION order: bw_ord[h2][jj], jj -> ks = kmap(w,jj)
  short8 bw_ord[2][16];
  {
    #pragma unroll
    for (int jj=0; jj<16; jj++){
      int ks = (w + (jj>>2) + 4*(jj&3)) & 15;
      int kof = ks*32 + hi*8;
      #pragma unroll
      for (int h2=0; h2<2; h2++){
        int c_loc = w*32 + h2*16 + row;                    // local col (gate = w)
        int wrow = (c_loc >> 5)*NH + u0 + (c_loc & 31);
        const float4* p4 = (const float4*)(Whh + (size_t)wrow*NH + kof);
        float4 lo = p4[0], hp = p4[1];
        short8 tv;
        tv[0]=(short)f2bf(lo.x); tv[1]=(short)f2bf(lo.y); tv[2]=(short)f2bf(lo.z); tv[3]=(short)f2bf(lo.w);
        tv[4]=(short)f2bf(hp.x); tv[5]=(short)f2bf(hp.y); tv[6]=(short)f2bf(hp.z); tv[7]=(short)f2bf(hp.w);
        bw_ord[h2][jj] = tv;
      }
    }
  }

  // ---- epilogue identity: thread -> (row r_e, unit-pair up)
  int r_e = tid >> 4, up = tid & 15;
  int be = b0 + r_e;
  float cst0 = c0[be*NH + u0 + 2*up];
  float cst1 = c0[be*NH + u0 + 2*up + 1];

  float2 bsv[4];
  #pragma unroll
  for (int gt=0; gt<4; gt++)
    bsv[gt] = *(const float2*)(base + (size_t)be*NG4 + gt*NH + u0 + 2*up);

  float2 tbv[4];
  {
    int tok0 = formulas[be*NT + 0];
    #pragma unroll
    for (int gt=0; gt<4; gt++)
      tbv[gt] = *(const float2*)(table + (size_t)tok0*NG4 + gt*NH + u0 + 2*up);
  }

  __syncthreads();   // ready[] init visible

  for (int t=0; t<NT; t++){
    const uint64* hrd64 = hbuf + (size_t)(t & 1)*HB64;
    uint64*       hwr64 = hbuf + (size_t)((t+1) & 1)*HB64;
    const uint32 etag = (uint32)t & 0xFFFFu;
    int par = t & 1;

    // ---- stage 4 owned chunks: poll global (tagged), pack, LDS, flag
    uint64 q[4][4];
    #pragma unroll
    for (int jj=0; jj<4; jj++){
      int ks = (w + 4*jj) & 15;
      const uint64* p = hrd64 + (size_t)(g*16 + ks)*256 + row*16 + hi*4;
      #pragma unroll
      for (int k=0;k<4;k++)
        q[jj][k] = __hip_atomic_load(p+k, __ATOMIC_RELAXED, __HIP_MEMORY_SCOPE_AGENT);
    }
    short8 paf[4];
    #pragma unroll
    for (int jj=0; jj<4; jj++){
      int ks = (w + 4*jj) & 15;
      const uint64* p = hrd64 + (size_t)(g*16 + ks)*256 + row*16 + hi*4;
      uint32 d = 0;
      #pragma unroll
      for (int k=0;k<4;k++) d |= (((uint32)(q[jj][k] >> 16)) ^ etag) & 0xFFFFu;
      int guard = 0;
      while (!__all(d == 0)){
        #pragma unroll
        for (int k=0;k<4;k++)
          q[jj][k] = __hip_atomic_load(p+k, __ATOMIC_RELAXED, __HIP_MEMORY_SCOPE_AGENT);
        d = 0;
        #pragma unroll
        for (int k=0;k<4;k++) d |= (((uint32)(q[jj][k] >> 16)) ^ etag) & 0xFFFFu;
        if (++guard > (1<<16)) break;
      }
      union { uint32 u[4]; short8 s8; } af;
      #pragma unroll
      for (int k=0;k<4;k++)
        af.u[k] = __builtin_amdgcn_perm((uint32)(q[jj][k] >> 32), (uint32)q[jj][k], 0x05040100u);
      paf[jj] = af.s8;
      *(short8*)(h_lds + ks*1024 + row*64 + slot*16) = af.s8;
      __hip_atomic_store(&ready[ks], t, __ATOMIC_RELEASE, __HIP_MEMORY_SCOPE_WORKGROUP);
    }

    // ---- MFMA stream: own chunks first (registers), then LDS after flag spin
    f32x4 acc0 = {0.f,0.f,0.f,0.f}, acc1 = {0.f,0.f,0.f,0.f};
    #pragma unroll
    for (int jj=0; jj<16; jj++){
      int ks = (w + (jj>>2) + 4*(jj&3)) & 15;
      short8 a;
      if (jj < 4){
        a = paf[jj];
      } else {
        int guard = 0;
        while (__hip_atomic_load(&ready[ks], __ATOMIC_ACQUIRE, __HIP_MEMORY_SCOPE_WORKGROUP) < t){
          if (++guard > (1<<20)) break;
        }
        a = *(const short8*)(h_lds + ks*1024 + row*64 + slot*16);
      }
      acc0 = __builtin_amdgcn_mfma_f32_16x16x32_bf16(a, bw_ord[0][jj], acc0, 0, 0, 0);
      acc1 = __builtin_amdgcn_mfma_f32_16x16x32_bf16(a, bw_ord[1][jj], acc1, 0, 0, 0);
    }

    // ---- scatter acc -> G[par]  (D: row=(lane>>4)*4+r, col=lane&15 per tile)
    {
      float* Gp = G[par];
      int rbase = hi*4;
      int col0 = (w*2+0)*16 + row;
      int col1 = (w*2+1)*16 + row;
      #pragma unroll
      for (int r4=0;r4<4;r4++){
        Gp[(rbase+r4)*132 + col0] = acc0[r4];
        Gp[(rbase+r4)*132 + col1] = acc1[r4];
      }
    }
    __syncthreads();   // the ONE sync per step

    // ---- fused gate epilogue (2 units per thread)
    float hn0, hn1;
    {
      const float* Gr = G[par] + r_e*132 + 2*up;
      float gi0 = Gr[0]   + tbv[0].x + bsv[0].x;
      float gi1 = Gr[1]   + tbv[0].y + bsv[0].y;
      float gf0 = Gr[32]  + tbv[1].x + bsv[1].x;
      float gf1 = Gr[33]  + tbv[1].y + bsv[1].y;
      float gg0 = Gr[64]  + tbv[2].x + bsv[2].x;
      float gg1 = Gr[65]  + tbv[2].y + bsv[2].y;
      float go0 = Gr[96]  + tbv[3].x + bsv[3].x;
      float go1 = Gr[97]  + tbv[3].y + bsv[3].y;
      float cn0 = sigf(gf0)*cst0 + sigf(gi0)*tanhfast(gg0);
      float cn1 = sigf(gf1)*cst1 + sigf(gi1)*tanhfast(gg1);
      cst0 = cn0; cst1 = cn1;
      hn0 = sigf(go0)*tanhfast(cn0);
      hn1 = sigf(go1)*tanhfast(cn1);
    }

    // ---- publish h_{t+1}: one tagged 8B store per thread (contiguous chunk)
    if (t < NT-1){
      uint64 pv = ((uint64)(((uint32)(t+1) << 16) | (uint32)f2bf(hn0)))
                | ((uint64)(((uint32)(t+1) << 16) | (uint32)f2bf(hn1)) << 32);
      __hip_atomic_store(hwr64 + (size_t)(g*16 + s)*256 + tid, pv,
                         __ATOMIC_RELAXED, __HIP_MEMORY_SCOPE_AGENT);
    }

    // ---- off-critical-path: output store + next-token table prefetch
    {
      float2 ov; ov.x = hn0; ov.y = hn1;
      *(float2*)(out + ((size_t)be*NT + t)*NH + u0 + 2*up) = ov;
    }
    if (t < NT-1){
      int tokn = formulas[be*NT + t + 1];
      #pragma unroll
      for (int gt=0; gt<4; gt++)
        tbv[gt] = *(const float2*)(table + (size_t)tokn*NG4 + gt*NH + u0 + 2*up);
    }
  }
}

extern "C" void kernel_launch(void* const* d_in, const int* in_sizes, int n_in,
                              void* d_out, int out_size, void* d_ws, size_t ws_size,
                              hipStream_t stream) {
  const float* lat      = (const float*)d_in[0];
  const int*   formulas = (const int*)d_in[1];
  const float* emb      = (const float*)d_in[2];
  const float* Wih      = (const float*)d_in[3];
  const float* bih      = (const float*)d_in[4];
  const float* Whh      = (const float*)d_in[5];
  const float* bhh      = (const float*)d_in[6];
  const float* Wh       = (const float*)d_in[7];
  const float* bh       = (const float*)d_in[8];
  const float* Wc       = (const float*)d_in[9];
  const float* bc       = (const float*)d_in[10];
  const float* Wo       = (const float*)d_in[11];
  const float* bo       = (const float*)d_in[12];
  float* out = (float*)d_out;

  char* ws = (char*)d_ws;
  float* meanv = (float*)ws;  ws += (size_t)NB*NCH*4;        // 64 KB
  float* c0    = (float*)ws;  ws += (size_t)NB*NH*4;         // 256 KB
  float* o0    = (float*)ws;  ws += (size_t)NB*NH*4;         // 256 KB
  float* table = (float*)ws;  ws += (size_t)NV*NG4*4;        // 4 MB
  float* base  = (float*)ws;  ws += (size_t)NB*NG4*4;        // 1 MB
  uint64* hbuf = (uint64*)ws; ws += (size_t)2*HB64*8;        // 512 KB (tagged, dbuf)

  // clear tags each launch — REQUIRED (stale tags from prior replay otherwise)
  hipMemsetAsync(hbuf, 0, (size_t)2*HB64*8, stream);
  k_mean <<<NB, 256, 0, stream>>>(lat, meanv);
  k_init <<<NB, NH, 0, stream>>>(meanv, Wh, bh, Wc, bc, Wo, bo, c0, o0, hbuf);
  k_table<<<dim3(NV, 8), 256, 0, stream>>>(emb, Wih, table);
  k_base <<<dim3(NB, 8), 256, 0, stream>>>(o0, Wih, bih, bhh, base);
  k_lstm <<<NB, 256, 0, stream>>>(Whh, formulas, table, base, c0, hbuf, out);
}